// Round 1
// baseline (112.674 us; speedup 1.0000x reference)
//
#include <hip/hip_runtime.h>

// NestedLoop: reference collapses to out = inp * prod_{i=0}^{7}(1 + 28*i).
// Memory-bound elementwise scale: float4 loads/stores, grid-stride loop.

__global__ __launch_bounds__(256) void NestedLoop_29626684408030_kernel(
    const float4* __restrict__ in, float4* __restrict__ out, int n4) {
    // Constant-fold the exact fp32 loop recurrence for the multiplier so the
    // scalar matches the reference's rounding path (all-constant -> folded).
    float s = 1.0f;
#pragma unroll
    for (int i = 0; i < 8; ++i) {
        float b = s * (float)i;
#pragma unroll
        for (int j = 0; j < 8; ++j) {
            s = s + b * (float)j;
        }
    }

    int idx = blockIdx.x * blockDim.x + threadIdx.x;
    int stride = gridDim.x * blockDim.x;
    for (int k = idx; k < n4; k += stride) {
        float4 v = in[k];
        v.x *= s; v.y *= s; v.z *= s; v.w *= s;
        out[k] = v;
    }
}

extern "C" void kernel_launch(void* const* d_in, const int* in_sizes, int n_in,
                              void* d_out, int out_size, void* d_ws, size_t ws_size,
                              hipStream_t stream) {
    const float4* in = (const float4*)d_in[0];
    float4* out = (float4*)d_out;
    int n = in_sizes[0];          // 8*8*1048576 = 67,108,864 floats
    int n4 = n / 4;               // 16,777,216 float4s (divisible)

    const int block = 256;
    int grid = (n4 + block - 1) / block;
    if (grid > 2048) grid = 2048;  // grid-stride: 256 CUs x 8 blocks/CU
    NestedLoop_29626684408030_kernel<<<grid, block, 0, stream>>>(in, out, n4);
}